// Round 1
// baseline (390.218 us; speedup 1.0000x reference)
//
#include <hip/hip_runtime.h>

// GCN_4492535792198: 3-layer GCN forward on MI355X (gfx950).
// N=50000, E=800000, D: 128->128->64. Outputs: logp[N,64], e1[N,128], e2[N,128], e3[N,64].
// R2: bf16 MFMA GEMM + bf16 gather aggregation.
// R3 (this round): L2-resident chunked aggregation. The gather table xw is 12.8 MB
//   (doesn't fit a 4 MiB per-XCD L2 -> ~70% of 204.8 MB/layer gather traffic went to L3).
//   Split D into 32-dim chunks (chunk table = 3.2 MB, L2-resident) and walk the edge
//   list once per chunk. Also: dinv folded into scan1, fillc init folded into scan3
//   (fill atomics on a rowptr copy), wprep merged with cnt-zeroing (16 -> 14 launches).

typedef __attribute__((ext_vector_type(8))) short short8;   // 8 x bf16 (4 VGPRs)
typedef __attribute__((ext_vector_type(4))) float f32x4;

__device__ __forceinline__ ushort f2bf(float f) {
    union { float f; unsigned u; } a; a.f = f;
    unsigned r = a.u + 0x7fffu + ((a.u >> 16) & 1u);   // RNE (finite data)
    return (ushort)(r >> 16);
}
__device__ __forceinline__ float bflo(unsigned u) { return __uint_as_float(u << 16); }
__device__ __forceinline__ float bfhi(unsigned u) { return __uint_as_float(u & 0xffff0000u); }

// ---------------- edge_index dtype detection (int32 vs int64) ----------------
__global__ void detect_dtype_kernel(const void* ei, int* flag) {
    int lane = threadIdx.x;                       // 64 threads
    long long v = ((const long long*)ei)[lane];
    int bad = (v < 0 || v >= (1LL << 32)) ? 1 : 0;
    unsigned long long m = __ballot(bad);
    if (lane == 0) *flag = (m == 0ULL) ? 1 : 0;   // 1 => int64
}

__device__ __forceinline__ int edge_at(const void* ei, int is64, long long i) {
    if (is64) return (int)((const long long*)ei)[i];
    return ((const int*)ei)[i];
}

// ---------------- prep: zero cnt + weight transpose to bf16 ----------------
// Wt[n][k] = bf16(W[k][n]). Grid = nzb + 160 blocks.
__global__ void prep_kernel(int* __restrict__ cnt, int n,
                            const float* __restrict__ W1, const float* __restrict__ W2,
                            const float* __restrict__ W3, ushort* __restrict__ Wt1,
                            ushort* __restrict__ Wt2, ushort* __restrict__ Wt3) {
    const int nzb = (n + 255) >> 8;
    const int b = blockIdx.x, tid = threadIdx.x;
    if (b < nzb) {
        int i = b * 256 + tid;
        if (i < n) cnt[i] = 0;
        return;
    }
    int i = (b - nzb) * 256 + tid;
    if (i < 16384) {
        int nn = i >> 7, k = i & 127;
        Wt1[i] = f2bf(W1[k * 128 + nn]);
    } else if (i < 32768) {
        int j = i - 16384; int nn = j >> 7, k = j & 127;
        Wt2[j] = f2bf(W2[k * 128 + nn]);
    } else if (i < 40960) {
        int j = i - 32768; int nn = j >> 7, k = j & 127;
        Wt3[j] = f2bf(W3[k * 64 + nn]);
    }
}

// ---------------- CSR build ----------------
__global__ void hist_kernel(const void* ei, const int* __restrict__ flag,
                            int* __restrict__ cnt, int E) {
    int e = blockIdx.x * blockDim.x + threadIdx.x;
    if (e >= E) return;
    int is64 = flag[0];
    int d = edge_at(ei, is64, (long long)E + e);
    atomicAdd(&cnt[d], 1);
}

__global__ void scan1_kernel(const int* __restrict__ cnt, int* __restrict__ rowptr,
                             int* __restrict__ bsum, float* __restrict__ dinv, int n) {
    int tid = threadIdx.x;
    int gid = blockIdx.x * 1024 + tid;
    int v = (gid < n) ? cnt[gid] : 0;
    if (gid < n) dinv[gid] = rsqrtf((float)(v + 1));   // +1 self loop
    int lane = tid & 63, wid = tid >> 6;
    int x = v;
#pragma unroll
    for (int off = 1; off < 64; off <<= 1) {
        int t = __shfl_up(x, off, 64);
        if (lane >= off) x += t;
    }
    __shared__ int wsum[16];
    if (lane == 63) wsum[wid] = x;
    __syncthreads();
    if (tid < 64) {
        int y = (lane < 16) ? wsum[lane] : 0;
#pragma unroll
        for (int off = 1; off < 16; off <<= 1) {
            int t = __shfl_up(y, off, 64);
            if (lane >= off) y += t;
        }
        if (lane < 16) wsum[lane] = y;
    }
    __syncthreads();
    int woff = (wid > 0) ? wsum[wid - 1] : 0;
    int incl = x + woff;
    if (gid < n) rowptr[gid] = incl - v;
    if (tid == 1023) bsum[blockIdx.x] = incl;
}

__global__ void scan2_kernel(const int* __restrict__ bsum, int* __restrict__ boff,
                             int nb, int* __restrict__ rowptr, int n, int E) {
    int lane = threadIdx.x;   // 64 threads
    int carry = 0;
    for (int base = 0; base < nb; base += 64) {
        int idx = base + lane;
        int v = (idx < nb) ? bsum[idx] : 0;
        int x = v;
#pragma unroll
        for (int off = 1; off < 64; off <<= 1) {
            int t = __shfl_up(x, off, 64);
            if (lane >= off) x += t;
        }
        if (idx < nb) boff[idx] = carry + x - v;
        carry += __shfl(x, 63, 64);
    }
    if (lane == 0) rowptr[n] = E;
}

// rowptr += block offset; also seed fillc with the final rowptr (fill atomics on it).
__global__ void scan3_kernel(int* __restrict__ rowptr, const int* __restrict__ boff,
                             int* __restrict__ fillc, int n) {
    int i = blockIdx.x * blockDim.x + threadIdx.x;
    if (i < n) {
        int v = rowptr[i] + boff[i >> 10];
        rowptr[i] = v;
        fillc[i] = v;
    }
}

__global__ void fill_kernel(const void* ei, const int* __restrict__ flag,
                            int* __restrict__ fillc, int* __restrict__ col, int E) {
    int e = blockIdx.x * blockDim.x + threadIdx.x;
    if (e >= E) return;
    int is64 = flag[0];
    int s = edge_at(ei, is64, e);
    int d = edge_at(ei, is64, (long long)E + e);
    int p = atomicAdd(&fillc[d], 1);
    col[p] = s;
}

// ---------------- MFMA GEMM: xw[M,DOUT](bf16) = relu?(A[M,128]) @ W ----------------
// 128-row x DOUT-col tile per 256-thread block (4 waves x 32 rows).
// LDS stride 136 bf16 (272 B): b128 fragment reads are perfectly bank-balanced.
template <int DOUT>
__global__ __launch_bounds__(256) void mfma_gemm_kernel(
    const float* __restrict__ A, const ushort* __restrict__ Wt,
    ushort* __restrict__ xw, int M, int act) {
    constexpr int NT = DOUT / 16;
    __shared__ ushort As[128 * 136];
    __shared__ ushort Ws[DOUT * 136];
    const int tid = threadIdx.x;
    const int r0 = blockIdx.x * 128;
    const int wid = tid >> 6;
    const int lane = tid & 63;
    const int m = lane & 15, quad = lane >> 4;

    // stage A: fp32 -> (relu) -> bf16, [row][k]
#pragma unroll
    for (int i = 0; i < 16; ++i) {
        int li = tid + i * 256;             // 0..4095 float4 slots
        int row = li >> 5, c4 = li & 31;
        float4 v = make_float4(0.f, 0.f, 0.f, 0.f);
        int gr = r0 + row;
        if (gr < M) v = ((const float4*)(A + (size_t)gr * 128))[c4];
        if (act) {
            v.x = fmaxf(v.x, 0.f); v.y = fmaxf(v.y, 0.f);
            v.z = fmaxf(v.z, 0.f); v.w = fmaxf(v.w, 0.f);
        }
        ushort4 u;
        u.x = f2bf(v.x); u.y = f2bf(v.y); u.z = f2bf(v.z); u.w = f2bf(v.w);
        *(ushort4*)&As[row * 136 + c4 * 4] = u;
    }
    // stage Wt: [n][k] bf16, contiguous 16B chunks
#pragma unroll
    for (int i = 0; i < DOUT / 16; ++i) {
        int li = tid + i * 256;             // uint4 slots over DOUT*16
        int n = li >> 4, c = li & 15;
        uint4 v = ((const uint4*)Wt)[li];
        *(uint4*)&Ws[n * 136 + c * 8] = v;
    }
    __syncthreads();

    f32x4 acc[2][NT];
#pragma unroll
    for (int rt = 0; rt < 2; ++rt)
#pragma unroll
        for (int nt = 0; nt < NT; ++nt) acc[rt][nt] = (f32x4){0.f, 0.f, 0.f, 0.f};

#pragma unroll
    for (int kt = 0; kt < 4; ++kt) {
        const int ko = kt * 32 + quad * 8;
        short8 af0 = *(const short8*)&As[(wid * 32 + m) * 136 + ko];
        short8 af1 = *(const short8*)&As[(wid * 32 + 16 + m) * 136 + ko];
        short8 bf_[NT];
#pragma unroll
        for (int nt = 0; nt < NT; ++nt)
            bf_[nt] = *(const short8*)&Ws[(nt * 16 + m) * 136 + ko];
#pragma unroll
        for (int nt = 0; nt < NT; ++nt) {
            acc[0][nt] = __builtin_amdgcn_mfma_f32_16x16x32_bf16(af0, bf_[nt], acc[0][nt], 0, 0, 0);
            acc[1][nt] = __builtin_amdgcn_mfma_f32_16x16x32_bf16(af1, bf_[nt], acc[1][nt], 0, 0, 0);
        }
    }
    // epilogue: C layout col=lane&15, row=quad*4+i (verified layout)
#pragma unroll
    for (int rt = 0; rt < 2; ++rt)
#pragma unroll
        for (int nt = 0; nt < NT; ++nt)
#pragma unroll
            for (int i = 0; i < 4; ++i) {
                int row = r0 + wid * 32 + rt * 16 + quad * 4 + i;
                if (row < M) xw[(size_t)row * DOUT + nt * 16 + m] = f2bf(acc[rt][nt][i]);
            }
}

// ---------------- aggregation (bf16 gather, L2-resident chunks) ----------------
// out = di*sum(dinv[s]*xw[s]) + di^2*xw[node] + b, computed in 32-dim chunks.
// PITCH = row pitch in uint4 (16 for D=128, 8 for D=64). Chunk = 4 uint4 = 32 dims
// -> per-chunk gather table is 50000*64B = 3.2 MB, fits a 4 MiB per-XCD L2.
// 4 lanes per node; chunk loop OUTER so co-resident blocks keep one chunk hot in L2.
template <int PITCH>
__global__ __launch_bounds__(256) void agg_chunk_kernel(
    const ushort* __restrict__ xw, const float* __restrict__ dinv,
    const int* __restrict__ rowptr, const int* __restrict__ col,
    const float* __restrict__ bias, float* __restrict__ out, int n) {
    constexpr int NC = PITCH / 4;          // chunks per row
    constexpr int D = PITCH * 8;
    const int tid = threadIdx.x;
    const int node = blockIdx.x * 64 + (tid >> 2);
    const int j = tid & 3;
    if (node >= n) return;
    const uint4* xw4 = (const uint4*)xw;
    const float di = dinv[node];
    const int p0 = rowptr[node], p1 = rowptr[node + 1];
    const float dii = di * di;

#pragma unroll
    for (int c = 0; c < NC; ++c) {
        const int base = c * 4 + j;        // uint4 index within row
        float acc[8];
#pragma unroll
        for (int i = 0; i < 8; ++i) acc[i] = 0.f;

        int p = p0;
        for (; p + 4 <= p1; p += 4) {       // 4 gathers in flight
            int s0 = col[p], s1 = col[p + 1], s2 = col[p + 2], s3 = col[p + 3];
            float w0 = dinv[s0], w1 = dinv[s1], w2 = dinv[s2], w3 = dinv[s3];
            uint4 v0 = xw4[(size_t)s0 * PITCH + base];
            uint4 v1 = xw4[(size_t)s1 * PITCH + base];
            uint4 v2 = xw4[(size_t)s2 * PITCH + base];
            uint4 v3 = xw4[(size_t)s3 * PITCH + base];
            acc[0] += w0 * bflo(v0.x); acc[1] += w0 * bfhi(v0.x);
            acc[2] += w0 * bflo(v0.y); acc[3] += w0 * bfhi(v0.y);
            acc[4] += w0 * bflo(v0.z); acc[5] += w0 * bfhi(v0.z);
            acc[6] += w0 * bflo(v0.w); acc[7] += w0 * bfhi(v0.w);
            acc[0] += w1 * bflo(v1.x); acc[1] += w1 * bfhi(v1.x);
            acc[2] += w1 * bflo(v1.y); acc[3] += w1 * bfhi(v1.y);
            acc[4] += w1 * bflo(v1.z); acc[5] += w1 * bfhi(v1.z);
            acc[6] += w1 * bflo(v1.w); acc[7] += w1 * bfhi(v1.w);
            acc[0] += w2 * bflo(v2.x); acc[1] += w2 * bfhi(v2.x);
            acc[2] += w2 * bflo(v2.y); acc[3] += w2 * bfhi(v2.y);
            acc[4] += w2 * bflo(v2.z); acc[5] += w2 * bfhi(v2.z);
            acc[6] += w2 * bflo(v2.w); acc[7] += w2 * bfhi(v2.w);
            acc[0] += w3 * bflo(v3.x); acc[1] += w3 * bfhi(v3.x);
            acc[2] += w3 * bflo(v3.y); acc[3] += w3 * bfhi(v3.y);
            acc[4] += w3 * bflo(v3.z); acc[5] += w3 * bfhi(v3.z);
            acc[6] += w3 * bflo(v3.w); acc[7] += w3 * bfhi(v3.w);
        }
        for (; p < p1; ++p) {
            int s = col[p];
            float w = dinv[s];
            uint4 v = xw4[(size_t)s * PITCH + base];
            acc[0] += w * bflo(v.x); acc[1] += w * bfhi(v.x);
            acc[2] += w * bflo(v.y); acc[3] += w * bfhi(v.y);
            acc[4] += w * bflo(v.z); acc[5] += w * bfhi(v.z);
            acc[6] += w * bflo(v.w); acc[7] += w * bfhi(v.w);
        }
        uint4 vs = xw4[(size_t)node * PITCH + base];
        float self[8] = { bflo(vs.x), bfhi(vs.x), bflo(vs.y), bfhi(vs.y),
                          bflo(vs.z), bfhi(vs.z), bflo(vs.w), bfhi(vs.w) };
        const float4 blo = ((const float4*)bias)[base * 2];
        const float4 bhi = ((const float4*)bias)[base * 2 + 1];
        const float bb[8] = { blo.x, blo.y, blo.z, blo.w, bhi.x, bhi.y, bhi.z, bhi.w };
        float o[8];
#pragma unroll
        for (int i = 0; i < 8; ++i) o[i] = di * acc[i] + dii * self[i] + bb[i];
        float* op = out + (size_t)node * D + base * 8;
        ((float4*)op)[0] = make_float4(o[0], o[1], o[2], o[3]);
        ((float4*)op)[1] = make_float4(o[4], o[5], o[6], o[7]);
    }
}

// ---------------- log_softmax over 64 classes: one wave per row ----------------
__global__ __launch_bounds__(256) void lsm_kernel(const float* __restrict__ e3,
                                                  float* __restrict__ logp, int n) {
    int row = blockIdx.x * 4 + (threadIdx.x >> 6);
    int lane = threadIdx.x & 63;
    if (row >= n) return;
    float v = e3[(size_t)row * 64 + lane];
    float m = v;
#pragma unroll
    for (int off = 32; off >= 1; off >>= 1) m = fmaxf(m, __shfl_xor(m, off, 64));
    float s = expf(v - m);
#pragma unroll
    for (int off = 32; off >= 1; off >>= 1) s += __shfl_xor(s, off, 64);
    logp[(size_t)row * 64 + lane] = v - m - logf(s);
}

// ---------------- driver ----------------
extern "C" void kernel_launch(void* const* d_in, const int* in_sizes, int n_in,
                              void* d_out, int out_size, void* d_ws, size_t ws_size,
                              hipStream_t stream) {
    const float* x  = (const float*)d_in[0];
    const void*  ei = d_in[1];
    const float* W1 = (const float*)d_in[2];
    const float* b1 = (const float*)d_in[3];
    const float* W2 = (const float*)d_in[4];
    const float* b2 = (const float*)d_in[5];
    const float* W3 = (const float*)d_in[6];
    const float* b3 = (const float*)d_in[7];
    float* out = (float*)d_out;

    const int N = in_sizes[0] / 128;   // 50000
    const int E = in_sizes[1] / 2;     // 800000

    char* w = (char*)d_ws;
    size_t off = 0;
    auto alloc = [&](size_t bytes) -> void* {
        void* p = w + off;
        off = (off + bytes + 255) & ~(size_t)255;
        return p;
    };
    int*    flag   = (int*)alloc(4);
    int*    cnt    = (int*)alloc((size_t)N * 4);
    int*    fillc  = (int*)alloc((size_t)N * 4);
    int*    rowptr = (int*)alloc((size_t)(N + 1) * 4);
    int*    bsum   = (int*)alloc(4096);
    int*    boff   = (int*)alloc(4096);
    float*  dinv   = (float*)alloc((size_t)N * 4);
    int*    col    = (int*)alloc((size_t)E * 4);
    ushort* xw     = (ushort*)alloc((size_t)N * 128 * 2);   // bf16
    ushort* Wt1    = (ushort*)alloc(16384 * 2);
    ushort* Wt2    = (ushort*)alloc(16384 * 2);
    ushort* Wt3    = (ushort*)alloc(8192 * 2);

    float* logp = out;
    float* e1 = out + (size_t)N * 64;
    float* e2 = e1 + (size_t)N * 128;
    float* e3 = e2 + (size_t)N * 128;

    const int nb = (N + 1023) / 1024;
    const int nzb = (N + 255) / 256;

    detect_dtype_kernel<<<1, 64, 0, stream>>>(ei, flag);
    prep_kernel<<<nzb + 160, 256, 0, stream>>>(cnt, N, W1, W2, W3, Wt1, Wt2, Wt3);
    hist_kernel<<<(E + 255) / 256, 256, 0, stream>>>(ei, flag, cnt, E);
    scan1_kernel<<<nb, 1024, 0, stream>>>(cnt, rowptr, bsum, dinv, N);
    scan2_kernel<<<1, 64, 0, stream>>>(bsum, boff, nb, rowptr, N, E);
    scan3_kernel<<<(N + 255) / 256, 256, 0, stream>>>(rowptr, boff, fillc, N);
    fill_kernel<<<(E + 255) / 256, 256, 0, stream>>>(ei, flag, fillc, col, E);

    const int gblocks = (N + 127) / 128;
    const int ablocks = (N + 63) / 64;
    // layer 1
    mfma_gemm_kernel<128><<<gblocks, 256, 0, stream>>>(x, Wt1, xw, N, 0);
    agg_chunk_kernel<16><<<ablocks, 256, 0, stream>>>(xw, dinv, rowptr, col, b1, e1, N);
    // layer 2 (ReLU on load)
    mfma_gemm_kernel<128><<<gblocks, 256, 0, stream>>>(e1, Wt2, xw, N, 1);
    agg_chunk_kernel<16><<<ablocks, 256, 0, stream>>>(xw, dinv, rowptr, col, b2, e2, N);
    // layer 3 (Dout=64)
    mfma_gemm_kernel<64><<<gblocks, 256, 0, stream>>>(e2, Wt3, xw, N, 1);
    agg_chunk_kernel<8><<<ablocks, 256, 0, stream>>>(xw, dinv, rowptr, col, b3, e3, N);
    // log_softmax
    lsm_kernel<<<(N + 3) / 4, 256, 0, stream>>>(e3, logp, N);
}

// Round 2
// 313.417 us; speedup vs baseline: 1.2450x; 1.2450x over previous
//
#include <hip/hip_runtime.h>

// GCN_4492535792198: 3-layer GCN forward on MI355X (gfx950).
// N=50000, E=800000, D: 128->128->64. Outputs: logp[N,64], e1[N,128], e2[N,128], e3[N,64].
// R4: revert R3 chunked agg (occupancy collapse + granule waste — measured 59us vs ~45us).
//   Back to R2 wide-granule gather (16 lanes x 16B = full 256B row, 3125 blocks).
//   New: (a) log-softmax fused into layer-3 agg; (b) agg1/2 emit relu'd bf16 copy so
//   GEMM2/3 read bf16 (half the A traffic, no convert); (c) one-kernel decoupled scan
//   (publish-then-spin, 49 blocks << capacity); detect+bsum-init folded into prep.
//   10 dispatches total.

typedef __attribute__((ext_vector_type(8))) short short8;   // 8 x bf16 (4 VGPRs)
typedef __attribute__((ext_vector_type(4))) float f32x4;

__device__ __forceinline__ ushort f2bf(float f) {
    union { float f; unsigned u; } a; a.f = f;
    unsigned r = a.u + 0x7fffu + ((a.u >> 16) & 1u);   // RNE (finite data)
    return (ushort)(r >> 16);
}
__device__ __forceinline__ float bflo(unsigned u) { return __uint_as_float(u << 16); }
__device__ __forceinline__ float bfhi(unsigned u) { return __uint_as_float(u & 0xffff0000u); }

__device__ __forceinline__ int edge_at(const void* ei, int is64, long long i) {
    if (is64) return (int)((const long long*)ei)[i];
    return ((const int*)ei)[i];
}

// ---------------- prep: zero cnt + weight transpose + detect dtype + bsum init ----
// Wt[n][k] = bf16(W[k][n]). Grid = nzb + 161 blocks.
__global__ void prep_kernel(int* __restrict__ cnt, int n,
                            const float* __restrict__ W1, const float* __restrict__ W2,
                            const float* __restrict__ W3, ushort* __restrict__ Wt1,
                            ushort* __restrict__ Wt2, ushort* __restrict__ Wt3,
                            const void* ei, int* __restrict__ flag,
                            int* __restrict__ bsum) {
    const int nzb = (n + 255) >> 8;
    const int b = blockIdx.x, tid = threadIdx.x;
    if (b < nzb) {
        int i = b * 256 + tid;
        if (i < n) cnt[i] = 0;
        return;
    }
    if (b == nzb + 160) {                 // detect + bsum sentinel block
        if (tid < 64) {
            bsum[tid] = -1;
            long long v = ((const long long*)ei)[tid];
            int bad = (v < 0 || v >= (1LL << 32)) ? 1 : 0;
            unsigned long long m = __ballot(bad);
            if (tid == 0) *flag = (m == 0ULL) ? 1 : 0;   // 1 => int64
        }
        return;
    }
    int i = (b - nzb) * 256 + tid;
    if (i < 16384) {
        int nn = i >> 7, k = i & 127;
        Wt1[i] = f2bf(W1[k * 128 + nn]);
    } else if (i < 32768) {
        int j = i - 16384; int nn = j >> 7, k = j & 127;
        Wt2[j] = f2bf(W2[k * 128 + nn]);
    } else if (i < 40960) {
        int j = i - 32768; int nn = j >> 7, k = j & 127;
        Wt3[j] = f2bf(W3[k * 64 + nn]);
    }
}

// ---------------- CSR build ----------------
__global__ void hist_kernel(const void* ei, const int* __restrict__ flag,
                            int* __restrict__ cnt, int E) {
    int e = blockIdx.x * blockDim.x + threadIdx.x;
    if (e >= E) return;
    int is64 = flag[0];
    int d = edge_at(ei, is64, (long long)E + e);
    atomicAdd(&cnt[d], 1);
}

// One-kernel scan: each 1024-thread block scans its 1024 counts, publishes its total
// (sentinel -1 -> value via atomicExch), spins for all predecessors' totals, then
// writes exclusive rowptr, fillc seed, and dinv. Requires nb <= 64 (N <= 65536) and
// nb <= co-resident capacity (49 blocks << 512 slots) — publish happens before spin,
// so no deadlock regardless of dispatch order.
__global__ void scan_fused_kernel(const int* __restrict__ cnt, int* __restrict__ rowptr,
                                  int* __restrict__ fillc, float* __restrict__ dinv,
                                  int* __restrict__ bsum, int n, int E) {
    const int tid = threadIdx.x;
    const int b = blockIdx.x;
    const int gid = b * 1024 + tid;
    int v = (gid < n) ? cnt[gid] : 0;
    if (gid < n) dinv[gid] = rsqrtf((float)(v + 1));   // +1 self loop
    const int lane = tid & 63, wid = tid >> 6;
    int x = v;
#pragma unroll
    for (int off = 1; off < 64; off <<= 1) {
        int t = __shfl_up(x, off, 64);
        if (lane >= off) x += t;
    }
    __shared__ int wsum[16];
    __shared__ int carry_s;
    if (lane == 63) wsum[wid] = x;
    __syncthreads();
    if (tid < 64) {
        int y = (lane < 16) ? wsum[lane] : 0;
#pragma unroll
        for (int off = 1; off < 16; off <<= 1) {
            int t = __shfl_up(y, off, 64);
            if (lane >= off) y += t;
        }
        if (lane < 16) wsum[lane] = y;
    }
    __syncthreads();
    const int woff = (wid > 0) ? wsum[wid - 1] : 0;
    const int incl = x + woff;
    const int total = wsum[15];
    if (tid == 0) atomicExch(&bsum[b], total);        // publish (device scope)
    if (tid < 64) {
        int c = 0;
        if (tid < b) {                                 // spin for predecessor totals
            int t;
            do { t = atomicAdd(&bsum[tid], 0); } while (t < 0);
            c = t;
        }
#pragma unroll
        for (int off = 1; off < 64; off <<= 1) c += __shfl_xor(c, off, 64);
        if (tid == 0) carry_s = c;
    }
    __syncthreads();
    const int carry = carry_s;
    if (gid < n) {
        int ex = carry + incl - v;                     // exclusive prefix
        rowptr[gid] = ex;
        fillc[gid] = ex;
    }
    if (b == 0 && tid == 0) rowptr[n] = E;
}

__global__ void fill_kernel(const void* ei, const int* __restrict__ flag,
                            int* __restrict__ fillc, int* __restrict__ col, int E) {
    int e = blockIdx.x * blockDim.x + threadIdx.x;
    if (e >= E) return;
    int is64 = flag[0];
    int s = edge_at(ei, is64, e);
    int d = edge_at(ei, is64, (long long)E + e);
    int p = atomicAdd(&fillc[d], 1);
    col[p] = s;
}

// ---------------- MFMA GEMM (fp32 input): xw[M,128](bf16) = A[M,128] @ W ----------
// 128-row x 128-col tile per 256-thread block (4 waves x 32 rows).
// LDS stride 136 bf16 (272 B): b128 fragment reads are perfectly bank-balanced.
__global__ __launch_bounds__(256) void mfma_gemm_f32_kernel(
    const float* __restrict__ A, const ushort* __restrict__ Wt,
    ushort* __restrict__ xw, int M) {
    constexpr int NT = 8;
    __shared__ ushort As[128 * 136];
    __shared__ ushort Ws[128 * 136];
    const int tid = threadIdx.x;
    const int r0 = blockIdx.x * 128;
    const int wid = tid >> 6;
    const int lane = tid & 63;
    const int m = lane & 15, quad = lane >> 4;

#pragma unroll
    for (int i = 0; i < 16; ++i) {
        int li = tid + i * 256;             // 0..4095 float4 slots
        int row = li >> 5, c4 = li & 31;
        float4 v = make_float4(0.f, 0.f, 0.f, 0.f);
        int gr = r0 + row;
        if (gr < M) v = ((const float4*)(A + (size_t)gr * 128))[c4];
        ushort4 u;
        u.x = f2bf(v.x); u.y = f2bf(v.y); u.z = f2bf(v.z); u.w = f2bf(v.w);
        *(ushort4*)&As[row * 136 + c4 * 4] = u;
    }
#pragma unroll
    for (int i = 0; i < 8; ++i) {
        int li = tid + i * 256;             // uint4 slots over 128*16
        int n = li >> 4, c = li & 15;
        uint4 v = ((const uint4*)Wt)[li];
        *(uint4*)&Ws[n * 136 + c * 8] = v;
    }
    __syncthreads();

    f32x4 acc[2][NT];
#pragma unroll
    for (int rt = 0; rt < 2; ++rt)
#pragma unroll
        for (int nt = 0; nt < NT; ++nt) acc[rt][nt] = (f32x4){0.f, 0.f, 0.f, 0.f};

#pragma unroll
    for (int kt = 0; kt < 4; ++kt) {
        const int ko = kt * 32 + quad * 8;
        short8 af0 = *(const short8*)&As[(wid * 32 + m) * 136 + ko];
        short8 af1 = *(const short8*)&As[(wid * 32 + 16 + m) * 136 + ko];
        short8 bf_[NT];
#pragma unroll
        for (int nt = 0; nt < NT; ++nt)
            bf_[nt] = *(const short8*)&Ws[(nt * 16 + m) * 136 + ko];
#pragma unroll
        for (int nt = 0; nt < NT; ++nt) {
            acc[0][nt] = __builtin_amdgcn_mfma_f32_16x16x32_bf16(af0, bf_[nt], acc[0][nt], 0, 0, 0);
            acc[1][nt] = __builtin_amdgcn_mfma_f32_16x16x32_bf16(af1, bf_[nt], acc[1][nt], 0, 0, 0);
        }
    }
#pragma unroll
    for (int rt = 0; rt < 2; ++rt)
#pragma unroll
        for (int nt = 0; nt < NT; ++nt)
#pragma unroll
            for (int i = 0; i < 4; ++i) {
                int row = r0 + wid * 32 + rt * 16 + quad * 4 + i;
                if (row < M) xw[(size_t)row * 128 + nt * 16 + m] = f2bf(acc[rt][nt][i]);
            }
}

// ---------------- MFMA GEMM (bf16 input, pre-relu'd): xw = A @ W ----------------
template <int DOUT>
__global__ __launch_bounds__(256) void mfma_gemm_b_kernel(
    const ushort* __restrict__ A, const ushort* __restrict__ Wt,
    ushort* __restrict__ xw, int M) {
    constexpr int NT = DOUT / 16;
    __shared__ ushort As[128 * 136];
    __shared__ ushort Ws[DOUT * 136];
    const int tid = threadIdx.x;
    const int r0 = blockIdx.x * 128;
    const int wid = tid >> 6;
    const int lane = tid & 63;
    const int m = lane & 15, quad = lane >> 4;

#pragma unroll
    for (int i = 0; i < 8; ++i) {
        int li = tid + i * 256;             // 2048 uint4 slots (128 rows x 16)
        int row = li >> 4, c = li & 15;
        uint4 v = make_uint4(0u, 0u, 0u, 0u);
        int gr = r0 + row;
        if (gr < M) v = ((const uint4*)A)[(size_t)gr * 16 + c];
        *(uint4*)&As[row * 136 + c * 8] = v;
    }
#pragma unroll
    for (int i = 0; i < DOUT / 16; ++i) {
        int li = tid + i * 256;
        int n = li >> 4, c = li & 15;
        uint4 v = ((const uint4*)Wt)[li];
        *(uint4*)&Ws[n * 136 + c * 8] = v;
    }
    __syncthreads();

    f32x4 acc[2][NT];
#pragma unroll
    for (int rt = 0; rt < 2; ++rt)
#pragma unroll
        for (int nt = 0; nt < NT; ++nt) acc[rt][nt] = (f32x4){0.f, 0.f, 0.f, 0.f};

#pragma unroll
    for (int kt = 0; kt < 4; ++kt) {
        const int ko = kt * 32 + quad * 8;
        short8 af0 = *(const short8*)&As[(wid * 32 + m) * 136 + ko];
        short8 af1 = *(const short8*)&As[(wid * 32 + 16 + m) * 136 + ko];
        short8 bf_[NT];
#pragma unroll
        for (int nt = 0; nt < NT; ++nt)
            bf_[nt] = *(const short8*)&Ws[(nt * 16 + m) * 136 + ko];
#pragma unroll
        for (int nt = 0; nt < NT; ++nt) {
            acc[0][nt] = __builtin_amdgcn_mfma_f32_16x16x32_bf16(af0, bf_[nt], acc[0][nt], 0, 0, 0);
            acc[1][nt] = __builtin_amdgcn_mfma_f32_16x16x32_bf16(af1, bf_[nt], acc[1][nt], 0, 0, 0);
        }
    }
#pragma unroll
    for (int rt = 0; rt < 2; ++rt)
#pragma unroll
        for (int nt = 0; nt < NT; ++nt)
#pragma unroll
            for (int i = 0; i < 4; ++i) {
                int row = r0 + wid * 32 + rt * 16 + quad * 4 + i;
                if (row < M) xw[(size_t)row * DOUT + nt * 16 + m] = f2bf(acc[rt][nt][i]);
            }
}

// ---------------- aggregation layers 1/2 (bf16 gather, full-row granule) ---------
// out = di*sum(dinv[s]*xw[s]) + di^2*xw[node] + b ; also emits xwb = bf16(relu(out))
// 16 lanes per node x 16B = full 256B row per gather (full cache lines).
__global__ __launch_bounds__(256) void agg12_kernel(
    const ushort* __restrict__ xw, const float* __restrict__ dinv,
    const int* __restrict__ rowptr, const int* __restrict__ col,
    const float* __restrict__ bias, float* __restrict__ out,
    ushort* __restrict__ xwb, int n) {
    const int tid = threadIdx.x;
    const int node = blockIdx.x * 16 + (tid >> 4);
    const int j = tid & 15;
    if (node >= n) return;
    const uint4* xw4 = (const uint4*)xw;   // row pitch = 16 uint4
    const float di = dinv[node];
    const int p0 = rowptr[node], p1 = rowptr[node + 1];
    float acc[8];
#pragma unroll
    for (int i = 0; i < 8; ++i) acc[i] = 0.f;

    int p = p0;
    for (; p + 4 <= p1; p += 4) {           // 4 gathers in flight
        int s0 = col[p], s1 = col[p + 1], s2 = col[p + 2], s3 = col[p + 3];
        float w0 = dinv[s0], w1 = dinv[s1], w2 = dinv[s2], w3 = dinv[s3];
        uint4 v0 = xw4[(size_t)s0 * 16 + j];
        uint4 v1 = xw4[(size_t)s1 * 16 + j];
        uint4 v2 = xw4[(size_t)s2 * 16 + j];
        uint4 v3 = xw4[(size_t)s3 * 16 + j];
        acc[0] += w0 * bflo(v0.x); acc[1] += w0 * bfhi(v0.x);
        acc[2] += w0 * bflo(v0.y); acc[3] += w0 * bfhi(v0.y);
        acc[4] += w0 * bflo(v0.z); acc[5] += w0 * bfhi(v0.z);
        acc[6] += w0 * bflo(v0.w); acc[7] += w0 * bfhi(v0.w);
        acc[0] += w1 * bflo(v1.x); acc[1] += w1 * bfhi(v1.x);
        acc[2] += w1 * bflo(v1.y); acc[3] += w1 * bfhi(v1.y);
        acc[4] += w1 * bflo(v1.z); acc[5] += w1 * bfhi(v1.z);
        acc[6] += w1 * bflo(v1.w); acc[7] += w1 * bfhi(v1.w);
        acc[0] += w2 * bflo(v2.x); acc[1] += w2 * bfhi(v2.x);
        acc[2] += w2 * bflo(v2.y); acc[3] += w2 * bfhi(v2.y);
        acc[4] += w2 * bflo(v2.z); acc[5] += w2 * bfhi(v2.z);
        acc[6] += w2 * bflo(v2.w); acc[7] += w2 * bfhi(v2.w);
        acc[0] += w3 * bflo(v3.x); acc[1] += w3 * bfhi(v3.x);
        acc[2] += w3 * bflo(v3.y); acc[3] += w3 * bfhi(v3.y);
        acc[4] += w3 * bflo(v3.z); acc[5] += w3 * bfhi(v3.z);
        acc[6] += w3 * bflo(v3.w); acc[7] += w3 * bfhi(v3.w);
    }
    for (; p < p1; ++p) {
        int s = col[p];
        float w = dinv[s];
        uint4 v = xw4[(size_t)s * 16 + j];
        acc[0] += w * bflo(v.x); acc[1] += w * bfhi(v.x);
        acc[2] += w * bflo(v.y); acc[3] += w * bfhi(v.y);
        acc[4] += w * bflo(v.z); acc[5] += w * bfhi(v.z);
        acc[6] += w * bflo(v.w); acc[7] += w * bfhi(v.w);
    }
    uint4 vs = xw4[(size_t)node * 16 + j];
    float self[8] = { bflo(vs.x), bfhi(vs.x), bflo(vs.y), bfhi(vs.y),
                      bflo(vs.z), bfhi(vs.z), bflo(vs.w), bfhi(vs.w) };
    const float4 blo = ((const float4*)bias)[2 * j];
    const float4 bhi = ((const float4*)bias)[2 * j + 1];
    const float bb[8] = { blo.x, blo.y, blo.z, blo.w, bhi.x, bhi.y, bhi.z, bhi.w };
    const float dii = di * di;
    float o[8];
#pragma unroll
    for (int i = 0; i < 8; ++i) o[i] = di * acc[i] + dii * self[i] + bb[i];
    float* op = out + (size_t)node * 128 + j * 8;
    ((float4*)op)[0] = make_float4(o[0], o[1], o[2], o[3]);
    ((float4*)op)[1] = make_float4(o[4], o[5], o[6], o[7]);
    // relu'd bf16 copy for the next GEMM
    union { ushort us[8]; uint4 v; } pk;
#pragma unroll
    for (int i = 0; i < 8; ++i) pk.us[i] = f2bf(fmaxf(o[i], 0.f));
    ((uint4*)xwb)[(size_t)node * 16 + j] = pk.v;
}

// ---------------- aggregation layer 3 (Dout=64) + fused log_softmax --------------
// 8 lanes per node; after e3 is formed, reduce max/sum across the 8-lane group.
__global__ __launch_bounds__(256) void agg3_lsm_kernel(
    const ushort* __restrict__ xw, const float* __restrict__ dinv,
    const int* __restrict__ rowptr, const int* __restrict__ col,
    const float* __restrict__ bias, float* __restrict__ e3,
    float* __restrict__ logp, int n) {
    const int tid = threadIdx.x;
    const int node = blockIdx.x * 32 + (tid >> 3);
    const int j = tid & 7;
    if (node >= n) return;
    const uint4* xw4 = (const uint4*)xw;   // row pitch = 8 uint4
    const float di = dinv[node];
    const int p0 = rowptr[node], p1 = rowptr[node + 1];
    float acc[8];
#pragma unroll
    for (int i = 0; i < 8; ++i) acc[i] = 0.f;

    int p = p0;
    for (; p + 4 <= p1; p += 4) {
        int s0 = col[p], s1 = col[p + 1], s2 = col[p + 2], s3 = col[p + 3];
        float w0 = dinv[s0], w1 = dinv[s1], w2 = dinv[s2], w3 = dinv[s3];
        uint4 v0 = xw4[(size_t)s0 * 8 + j];
        uint4 v1 = xw4[(size_t)s1 * 8 + j];
        uint4 v2 = xw4[(size_t)s2 * 8 + j];
        uint4 v3 = xw4[(size_t)s3 * 8 + j];
        acc[0] += w0 * bflo(v0.x); acc[1] += w0 * bfhi(v0.x);
        acc[2] += w0 * bflo(v0.y); acc[3] += w0 * bfhi(v0.y);
        acc[4] += w0 * bflo(v0.z); acc[5] += w0 * bfhi(v0.z);
        acc[6] += w0 * bflo(v0.w); acc[7] += w0 * bfhi(v0.w);
        acc[0] += w1 * bflo(v1.x); acc[1] += w1 * bfhi(v1.x);
        acc[2] += w1 * bflo(v1.y); acc[3] += w1 * bfhi(v1.y);
        acc[4] += w1 * bflo(v1.z); acc[5] += w1 * bfhi(v1.z);
        acc[6] += w1 * bflo(v1.w); acc[7] += w1 * bfhi(v1.w);
        acc[0] += w2 * bflo(v2.x); acc[1] += w2 * bfhi(v2.x);
        acc[2] += w2 * bflo(v2.y); acc[3] += w2 * bfhi(v2.y);
        acc[4] += w2 * bflo(v2.z); acc[5] += w2 * bfhi(v2.z);
        acc[6] += w2 * bflo(v2.w); acc[7] += w2 * bfhi(v2.w);
        acc[0] += w3 * bflo(v3.x); acc[1] += w3 * bfhi(v3.x);
        acc[2] += w3 * bflo(v3.y); acc[3] += w3 * bfhi(v3.y);
        acc[4] += w3 * bflo(v3.z); acc[5] += w3 * bfhi(v3.z);
        acc[6] += w3 * bflo(v3.w); acc[7] += w3 * bfhi(v3.w);
    }
    for (; p < p1; ++p) {
        int s = col[p];
        float w = dinv[s];
        uint4 v = xw4[(size_t)s * 8 + j];
        acc[0] += w * bflo(v.x); acc[1] += w * bfhi(v.x);
        acc[2] += w * bflo(v.y); acc[3] += w * bfhi(v.y);
        acc[4] += w * bflo(v.z); acc[5] += w * bfhi(v.z);
        acc[6] += w * bflo(v.w); acc[7] += w * bfhi(v.w);
    }
    uint4 vs = xw4[(size_t)node * 8 + j];
    float self[8] = { bflo(vs.x), bfhi(vs.x), bflo(vs.y), bfhi(vs.y),
                      bflo(vs.z), bfhi(vs.z), bflo(vs.w), bfhi(vs.w) };
    const float4 blo = ((const float4*)bias)[2 * j];
    const float4 bhi = ((const float4*)bias)[2 * j + 1];
    const float bb[8] = { blo.x, blo.y, blo.z, blo.w, bhi.x, bhi.y, bhi.z, bhi.w };
    const float dii = di * di;
    float o[8];
#pragma unroll
    for (int i = 0; i < 8; ++i) o[i] = di * acc[i] + dii * self[i] + bb[i];
    float* ep = e3 + (size_t)node * 64 + j * 8;
    ((float4*)ep)[0] = make_float4(o[0], o[1], o[2], o[3]);
    ((float4*)ep)[1] = make_float4(o[4], o[5], o[6], o[7]);
    // fused log_softmax over the 8-lane group (lanes of one node are consecutive)
    float m = o[0];
#pragma unroll
    for (int i = 1; i < 8; ++i) m = fmaxf(m, o[i]);
#pragma unroll
    for (int off = 1; off < 8; off <<= 1) m = fmaxf(m, __shfl_xor(m, off, 64));
    float s = 0.f;
#pragma unroll
    for (int i = 0; i < 8; ++i) s += expf(o[i] - m);
#pragma unroll
    for (int off = 1; off < 8; off <<= 1) s += __shfl_xor(s, off, 64);
    const float ls = m + logf(s);
    float* lp = logp + (size_t)node * 64 + j * 8;
    ((float4*)lp)[0] = make_float4(o[0] - ls, o[1] - ls, o[2] - ls, o[3] - ls);
    ((float4*)lp)[1] = make_float4(o[4] - ls, o[5] - ls, o[6] - ls, o[7] - ls);
}

// ---------------- driver ----------------
extern "C" void kernel_launch(void* const* d_in, const int* in_sizes, int n_in,
                              void* d_out, int out_size, void* d_ws, size_t ws_size,
                              hipStream_t stream) {
    const float* x  = (const float*)d_in[0];
    const void*  ei = d_in[1];
    const float* W1 = (const float*)d_in[2];
    const float* b1 = (const float*)d_in[3];
    const float* W2 = (const float*)d_in[4];
    const float* b2 = (const float*)d_in[5];
    const float* W3 = (const float*)d_in[6];
    const float* b3 = (const float*)d_in[7];
    float* out = (float*)d_out;

    const int N = in_sizes[0] / 128;   // 50000
    const int E = in_sizes[1] / 2;     // 800000

    char* w = (char*)d_ws;
    size_t off = 0;
    auto alloc = [&](size_t bytes) -> void* {
        void* p = w + off;
        off = (off + bytes + 255) & ~(size_t)255;
        return p;
    };
    int*    flag   = (int*)alloc(4);
    int*    cnt    = (int*)alloc((size_t)N * 4);
    int*    fillc  = (int*)alloc((size_t)N * 4);
    int*    rowptr = (int*)alloc((size_t)(N + 1) * 4);
    int*    bsum   = (int*)alloc(4096);
    float*  dinv   = (float*)alloc((size_t)N * 4);
    int*    col    = (int*)alloc((size_t)E * 4);
    ushort* xw     = (ushort*)alloc((size_t)N * 128 * 2);   // bf16 GEMM output
    ushort* xwb    = (ushort*)alloc((size_t)N * 128 * 2);   // bf16 relu'd agg output
    ushort* Wt1    = (ushort*)alloc(16384 * 2);
    ushort* Wt2    = (ushort*)alloc(16384 * 2);
    ushort* Wt3    = (ushort*)alloc(8192 * 2);

    float* logp = out;
    float* e1 = out + (size_t)N * 64;
    float* e2 = e1 + (size_t)N * 128;
    float* e3 = e2 + (size_t)N * 128;

    const int nb = (N + 1023) / 1024;          // 49 (must be <= 64)
    const int nzb = (N + 255) / 256;

    prep_kernel<<<nzb + 161, 256, 0, stream>>>(cnt, N, W1, W2, W3, Wt1, Wt2, Wt3,
                                               ei, flag, bsum);
    hist_kernel<<<(E + 255) / 256, 256, 0, stream>>>(ei, flag, cnt, E);
    scan_fused_kernel<<<nb, 1024, 0, stream>>>(cnt, rowptr, fillc, dinv, bsum, N, E);
    fill_kernel<<<(E + 255) / 256, 256, 0, stream>>>(ei, flag, fillc, col, E);

    const int gblocks = (N + 127) / 128;
    // layer 1
    mfma_gemm_f32_kernel<<<gblocks, 256, 0, stream>>>(x, Wt1, xw, N);
    agg12_kernel<<<(N + 15) / 16, 256, 0, stream>>>(xw, dinv, rowptr, col, b1, e1, xwb, N);
    // layer 2
    mfma_gemm_b_kernel<128><<<gblocks, 256, 0, stream>>>(xwb, Wt2, xw, N);
    agg12_kernel<<<(N + 15) / 16, 256, 0, stream>>>(xw, dinv, rowptr, col, b2, e2, xwb, N);
    // layer 3 (Dout=64) + log_softmax
    mfma_gemm_b_kernel<64><<<gblocks, 256, 0, stream>>>(xwb, Wt3, xw, N);
    agg3_lsm_kernel<<<(N + 31) / 32, 256, 0, stream>>>(xw, dinv, rowptr, col, b3, e3, logp, N);
}

// Round 3
// 275.589 us; speedup vs baseline: 1.4159x; 1.1373x over previous
//
#include <hip/hip_runtime.h>

// GCN_4492535792198: 3-layer GCN forward on MI355X (gfx950).
// N=50000, E=800000, D: 128->128->64. Outputs: logp[N,64], e1[N,128], e2[N,128], e3[N,64].
// R5: replace CSR build (hist+scan+fill, ~85us) with a one-pass fixed-capacity slot
//   table: slots[N][64], p=atomicAdd(&cnt[d],1). Degree is Poisson(16); P(deg>64)
//   ~5e-19/node -> cap 64 never overflows (guarded anyway). dinv array removed:
//   agg computes rsqrtf(cnt[s]+1) inline (VALU was 18% busy; cnt gather = dinv gather).
//   Agg inner loop hand-pipelined (prefetch next col quad under outstanding gathers).
//   8 dispatches (was 10).

typedef __attribute__((ext_vector_type(8))) short short8;   // 8 x bf16 (4 VGPRs)
typedef __attribute__((ext_vector_type(4))) float f32x4;

#define SLOT_CAP 64

__device__ __forceinline__ ushort f2bf(float f) {
    union { float f; unsigned u; } a; a.f = f;
    unsigned r = a.u + 0x7fffu + ((a.u >> 16) & 1u);   // RNE (finite data)
    return (ushort)(r >> 16);
}
__device__ __forceinline__ float bflo(unsigned u) { return __uint_as_float(u << 16); }
__device__ __forceinline__ float bfhi(unsigned u) { return __uint_as_float(u & 0xffff0000u); }

__device__ __forceinline__ int edge_at(const void* ei, int is64, long long i) {
    if (is64) return (int)((const long long*)ei)[i];
    return ((const int*)ei)[i];
}

// ---------------- prep: zero cnt + weight transpose + detect dtype ----------------
// Wt[n][k] = bf16(W[k][n]). Grid = nzb + 161 blocks.
__global__ void prep_kernel(int* __restrict__ cnt, int n,
                            const float* __restrict__ W1, const float* __restrict__ W2,
                            const float* __restrict__ W3, ushort* __restrict__ Wt1,
                            ushort* __restrict__ Wt2, ushort* __restrict__ Wt3,
                            const void* ei, int* __restrict__ flag) {
    const int nzb = (n + 255) >> 8;
    const int b = blockIdx.x, tid = threadIdx.x;
    if (b < nzb) {
        int i = b * 256 + tid;
        if (i < n) cnt[i] = 0;
        return;
    }
    if (b == nzb + 160) {                 // dtype-detect block
        if (tid < 64) {
            long long v = ((const long long*)ei)[tid];
            int bad = (v < 0 || v >= (1LL << 32)) ? 1 : 0;
            unsigned long long m = __ballot(bad);
            if (tid == 0) *flag = (m == 0ULL) ? 1 : 0;   // 1 => int64
        }
        return;
    }
    int i = (b - nzb) * 256 + tid;
    if (i < 16384) {
        int nn = i >> 7, k = i & 127;
        Wt1[i] = f2bf(W1[k * 128 + nn]);
    } else if (i < 32768) {
        int j = i - 16384; int nn = j >> 7, k = j & 127;
        Wt2[j] = f2bf(W2[k * 128 + nn]);
    } else if (i < 40960) {
        int j = i - 32768; int nn = j >> 7, k = j & 127;
        Wt3[j] = f2bf(W3[k * 64 + nn]);
    }
}

// ---------------- one-pass slot fill: cnt[d]++, slots[d*64+p] = s ----------------
__global__ void fillslots_kernel(const void* ei, const int* __restrict__ flag,
                                 int* __restrict__ cnt, int* __restrict__ slots, int E) {
    int e = blockIdx.x * blockDim.x + threadIdx.x;
    if (e >= E) return;
    int is64 = flag[0];
    int s = edge_at(ei, is64, e);
    int d = edge_at(ei, is64, (long long)E + e);
    int p = atomicAdd(&cnt[d], 1);
    if (p < SLOT_CAP) slots[(d << 6) + p] = s;
}

// ---------------- MFMA GEMM (fp32 input): xw[M,128](bf16) = A[M,128] @ W ----------
// 128-row x 128-col tile per 256-thread block (4 waves x 32 rows).
// LDS stride 136 bf16 (272 B): b128 fragment reads are perfectly bank-balanced.
__global__ __launch_bounds__(256) void mfma_gemm_f32_kernel(
    const float* __restrict__ A, const ushort* __restrict__ Wt,
    ushort* __restrict__ xw, int M) {
    constexpr int NT = 8;
    __shared__ ushort As[128 * 136];
    __shared__ ushort Ws[128 * 136];
    const int tid = threadIdx.x;
    const int r0 = blockIdx.x * 128;
    const int wid = tid >> 6;
    const int lane = tid & 63;
    const int m = lane & 15, quad = lane >> 4;

#pragma unroll
    for (int i = 0; i < 16; ++i) {
        int li = tid + i * 256;             // 0..4095 float4 slots
        int row = li >> 5, c4 = li & 31;
        float4 v = make_float4(0.f, 0.f, 0.f, 0.f);
        int gr = r0 + row;
        if (gr < M) v = ((const float4*)(A + (size_t)gr * 128))[c4];
        ushort4 u;
        u.x = f2bf(v.x); u.y = f2bf(v.y); u.z = f2bf(v.z); u.w = f2bf(v.w);
        *(ushort4*)&As[row * 136 + c4 * 4] = u;
    }
#pragma unroll
    for (int i = 0; i < 8; ++i) {
        int li = tid + i * 256;             // uint4 slots over 128*16
        int n = li >> 4, c = li & 15;
        uint4 v = ((const uint4*)Wt)[li];
        *(uint4*)&Ws[n * 136 + c * 8] = v;
    }
    __syncthreads();

    f32x4 acc[2][NT];
#pragma unroll
    for (int rt = 0; rt < 2; ++rt)
#pragma unroll
        for (int nt = 0; nt < NT; ++nt) acc[rt][nt] = (f32x4){0.f, 0.f, 0.f, 0.f};

#pragma unroll
    for (int kt = 0; kt < 4; ++kt) {
        const int ko = kt * 32 + quad * 8;
        short8 af0 = *(const short8*)&As[(wid * 32 + m) * 136 + ko];
        short8 af1 = *(const short8*)&As[(wid * 32 + 16 + m) * 136 + ko];
        short8 bf_[NT];
#pragma unroll
        for (int nt = 0; nt < NT; ++nt)
            bf_[nt] = *(const short8*)&Ws[(nt * 16 + m) * 136 + ko];
#pragma unroll
        for (int nt = 0; nt < NT; ++nt) {
            acc[0][nt] = __builtin_amdgcn_mfma_f32_16x16x32_bf16(af0, bf_[nt], acc[0][nt], 0, 0, 0);
            acc[1][nt] = __builtin_amdgcn_mfma_f32_16x16x32_bf16(af1, bf_[nt], acc[1][nt], 0, 0, 0);
        }
    }
#pragma unroll
    for (int rt = 0; rt < 2; ++rt)
#pragma unroll
        for (int nt = 0; nt < NT; ++nt)
#pragma unroll
            for (int i = 0; i < 4; ++i) {
                int row = r0 + wid * 32 + rt * 16 + quad * 4 + i;
                if (row < M) xw[(size_t)row * 128 + nt * 16 + m] = f2bf(acc[rt][nt][i]);
            }
}

// ---------------- MFMA GEMM (bf16 input, pre-relu'd): xw = A @ W ----------------
template <int DOUT>
__global__ __launch_bounds__(256) void mfma_gemm_b_kernel(
    const ushort* __restrict__ A, const ushort* __restrict__ Wt,
    ushort* __restrict__ xw, int M) {
    constexpr int NT = DOUT / 16;
    __shared__ ushort As[128 * 136];
    __shared__ ushort Ws[DOUT * 136];
    const int tid = threadIdx.x;
    const int r0 = blockIdx.x * 128;
    const int wid = tid >> 6;
    const int lane = tid & 63;
    const int m = lane & 15, quad = lane >> 4;

#pragma unroll
    for (int i = 0; i < 8; ++i) {
        int li = tid + i * 256;             // 2048 uint4 slots (128 rows x 16)
        int row = li >> 4, c = li & 15;
        uint4 v = make_uint4(0u, 0u, 0u, 0u);
        int gr = r0 + row;
        if (gr < M) v = ((const uint4*)A)[(size_t)gr * 16 + c];
        *(uint4*)&As[row * 136 + c * 8] = v;
    }
#pragma unroll
    for (int i = 0; i < DOUT / 16; ++i) {
        int li = tid + i * 256;
        int n = li >> 4, c = li & 15;
        uint4 v = ((const uint4*)Wt)[li];
        *(uint4*)&Ws[n * 136 + c * 8] = v;
    }
    __syncthreads();

    f32x4 acc[2][NT];
#pragma unroll
    for (int rt = 0; rt < 2; ++rt)
#pragma unroll
        for (int nt = 0; nt < NT; ++nt) acc[rt][nt] = (f32x4){0.f, 0.f, 0.f, 0.f};

#pragma unroll
    for (int kt = 0; kt < 4; ++kt) {
        const int ko = kt * 32 + quad * 8;
        short8 af0 = *(const short8*)&As[(wid * 32 + m) * 136 + ko];
        short8 af1 = *(const short8*)&As[(wid * 32 + 16 + m) * 136 + ko];
        short8 bf_[NT];
#pragma unroll
        for (int nt = 0; nt < NT; ++nt)
            bf_[nt] = *(const short8*)&Ws[(nt * 16 + m) * 136 + ko];
#pragma unroll
        for (int nt = 0; nt < NT; ++nt) {
            acc[0][nt] = __builtin_amdgcn_mfma_f32_16x16x32_bf16(af0, bf_[nt], acc[0][nt], 0, 0, 0);
            acc[1][nt] = __builtin_amdgcn_mfma_f32_16x16x32_bf16(af1, bf_[nt], acc[1][nt], 0, 0, 0);
        }
    }
#pragma unroll
    for (int rt = 0; rt < 2; ++rt)
#pragma unroll
        for (int nt = 0; nt < NT; ++nt)
#pragma unroll
            for (int i = 0; i < 4; ++i) {
                int row = r0 + wid * 32 + rt * 16 + quad * 4 + i;
                if (row < M) xw[(size_t)row * DOUT + nt * 16 + m] = f2bf(acc[rt][nt][i]);
            }
}

// ---------------- aggregation layers 1/2 (bf16 gather, slot-based) --------------
// out = di*sum(w_s*xw[s]) + di^2*xw[node] + b, w_s = rsqrt(cnt[s]+1), di likewise.
// 16 lanes per node x 16B = full 256B row per gather. Hand-pipelined: next col quad
// prefetched while 4 row-gathers + 4 cnt-gathers are outstanding.
__global__ __launch_bounds__(256) void agg12_kernel(
    const ushort* __restrict__ xw, const int* __restrict__ cnt,
    const int* __restrict__ slots, const float* __restrict__ bias,
    float* __restrict__ out, ushort* __restrict__ xwb, int n) {
    const int tid = threadIdx.x;
    const int node = blockIdx.x * 16 + (tid >> 4);
    const int j = tid & 15;
    if (node >= n) return;
    const uint4* xw4 = (const uint4*)xw;   // row pitch = 16 uint4
    const int degf = cnt[node];
    const int deg = (degf < SLOT_CAP) ? degf : SLOT_CAP;
    const float di = rsqrtf((float)(degf + 1));
    const int base = node << 6;
    float acc[8];
#pragma unroll
    for (int i = 0; i < 8; ++i) acc[i] = 0.f;

    int p = 0;
    int4 c;
    if (deg >= 4) c = *(const int4*)&slots[base];
    while (p + 4 <= deg) {
        const int s0 = c.x, s1 = c.y, s2 = c.z, s3 = c.w;
        const int g0 = cnt[s0], g1 = cnt[s1], g2 = cnt[s2], g3 = cnt[s3];
        uint4 v0 = xw4[(size_t)s0 * 16 + j];
        uint4 v1 = xw4[(size_t)s1 * 16 + j];
        uint4 v2 = xw4[(size_t)s2 * 16 + j];
        uint4 v3 = xw4[(size_t)s3 * 16 + j];
        p += 4;
        if (p + 4 <= deg) c = *(const int4*)&slots[base + p];
        const float w0 = rsqrtf((float)(g0 + 1));
        const float w1 = rsqrtf((float)(g1 + 1));
        const float w2 = rsqrtf((float)(g2 + 1));
        const float w3 = rsqrtf((float)(g3 + 1));
        acc[0] += w0 * bflo(v0.x); acc[1] += w0 * bfhi(v0.x);
        acc[2] += w0 * bflo(v0.y); acc[3] += w0 * bfhi(v0.y);
        acc[4] += w0 * bflo(v0.z); acc[5] += w0 * bfhi(v0.z);
        acc[6] += w0 * bflo(v0.w); acc[7] += w0 * bfhi(v0.w);
        acc[0] += w1 * bflo(v1.x); acc[1] += w1 * bfhi(v1.x);
        acc[2] += w1 * bflo(v1.y); acc[3] += w1 * bfhi(v1.y);
        acc[4] += w1 * bflo(v1.z); acc[5] += w1 * bfhi(v1.z);
        acc[6] += w1 * bflo(v1.w); acc[7] += w1 * bfhi(v1.w);
        acc[0] += w2 * bflo(v2.x); acc[1] += w2 * bfhi(v2.x);
        acc[2] += w2 * bflo(v2.y); acc[3] += w2 * bfhi(v2.y);
        acc[4] += w2 * bflo(v2.z); acc[5] += w2 * bfhi(v2.z);
        acc[6] += w2 * bflo(v2.w); acc[7] += w2 * bfhi(v2.w);
        acc[0] += w3 * bflo(v3.x); acc[1] += w3 * bfhi(v3.x);
        acc[2] += w3 * bflo(v3.y); acc[3] += w3 * bfhi(v3.y);
        acc[4] += w3 * bflo(v3.z); acc[5] += w3 * bfhi(v3.z);
        acc[6] += w3 * bflo(v3.w); acc[7] += w3 * bfhi(v3.w);
    }
    for (; p < deg; ++p) {
        const int s = slots[base + p];
        const float w = rsqrtf((float)(cnt[s] + 1));
        uint4 v = xw4[(size_t)s * 16 + j];
        acc[0] += w * bflo(v.x); acc[1] += w * bfhi(v.x);
        acc[2] += w * bflo(v.y); acc[3] += w * bfhi(v.y);
        acc[4] += w * bflo(v.z); acc[5] += w * bfhi(v.z);
        acc[6] += w * bflo(v.w); acc[7] += w * bfhi(v.w);
    }
    uint4 vs = xw4[(size_t)node * 16 + j];
    float self[8] = { bflo(vs.x), bfhi(vs.x), bflo(vs.y), bfhi(vs.y),
                      bflo(vs.z), bfhi(vs.z), bflo(vs.w), bfhi(vs.w) };
    const float4 blo = ((const float4*)bias)[2 * j];
    const float4 bhi = ((const float4*)bias)[2 * j + 1];
    const float bb[8] = { blo.x, blo.y, blo.z, blo.w, bhi.x, bhi.y, bhi.z, bhi.w };
    const float dii = di * di;
    float o[8];
#pragma unroll
    for (int i = 0; i < 8; ++i) o[i] = di * acc[i] + dii * self[i] + bb[i];
    float* op = out + (size_t)node * 128 + j * 8;
    ((float4*)op)[0] = make_float4(o[0], o[1], o[2], o[3]);
    ((float4*)op)[1] = make_float4(o[4], o[5], o[6], o[7]);
    // relu'd bf16 copy for the next GEMM
    union { ushort us[8]; uint4 v; } pk;
#pragma unroll
    for (int i = 0; i < 8; ++i) pk.us[i] = f2bf(fmaxf(o[i], 0.f));
    ((uint4*)xwb)[(size_t)node * 16 + j] = pk.v;
}

// ---------------- aggregation layer 3 (Dout=64) + fused log_softmax --------------
// 8 lanes per node; after e3 is formed, reduce max/sum across the 8-lane group.
__global__ __launch_bounds__(256) void agg3_lsm_kernel(
    const ushort* __restrict__ xw, const int* __restrict__ cnt,
    const int* __restrict__ slots, const float* __restrict__ bias,
    float* __restrict__ e3, float* __restrict__ logp, int n) {
    const int tid = threadIdx.x;
    const int node = blockIdx.x * 32 + (tid >> 3);
    const int j = tid & 7;
    if (node >= n) return;
    const uint4* xw4 = (const uint4*)xw;   // row pitch = 8 uint4
    const int degf = cnt[node];
    const int deg = (degf < SLOT_CAP) ? degf : SLOT_CAP;
    const float di = rsqrtf((float)(degf + 1));
    const int base = node << 6;
    float acc[8];
#pragma unroll
    for (int i = 0; i < 8; ++i) acc[i] = 0.f;

    int p = 0;
    int4 c;
    if (deg >= 4) c = *(const int4*)&slots[base];
    while (p + 4 <= deg) {
        const int s0 = c.x, s1 = c.y, s2 = c.z, s3 = c.w;
        const int g0 = cnt[s0], g1 = cnt[s1], g2 = cnt[s2], g3 = cnt[s3];
        uint4 v0 = xw4[(size_t)s0 * 8 + j];
        uint4 v1 = xw4[(size_t)s1 * 8 + j];
        uint4 v2 = xw4[(size_t)s2 * 8 + j];
        uint4 v3 = xw4[(size_t)s3 * 8 + j];
        p += 4;
        if (p + 4 <= deg) c = *(const int4*)&slots[base + p];
        const float w0 = rsqrtf((float)(g0 + 1));
        const float w1 = rsqrtf((float)(g1 + 1));
        const float w2 = rsqrtf((float)(g2 + 1));
        const float w3 = rsqrtf((float)(g3 + 1));
        acc[0] += w0 * bflo(v0.x); acc[1] += w0 * bfhi(v0.x);
        acc[2] += w0 * bflo(v0.y); acc[3] += w0 * bfhi(v0.y);
        acc[4] += w0 * bflo(v0.z); acc[5] += w0 * bfhi(v0.z);
        acc[6] += w0 * bflo(v0.w); acc[7] += w0 * bfhi(v0.w);
        acc[0] += w1 * bflo(v1.x); acc[1] += w1 * bfhi(v1.x);
        acc[2] += w1 * bflo(v1.y); acc[3] += w1 * bfhi(v1.y);
        acc[4] += w1 * bflo(v1.z); acc[5] += w1 * bfhi(v1.z);
        acc[6] += w1 * bflo(v1.w); acc[7] += w1 * bfhi(v1.w);
        acc[0] += w2 * bflo(v2.x); acc[1] += w2 * bfhi(v2.x);
        acc[2] += w2 * bflo(v2.y); acc[3] += w2 * bfhi(v2.y);
        acc[4] += w2 * bflo(v2.z); acc[5] += w2 * bfhi(v2.z);
        acc[6] += w2 * bflo(v2.w); acc[7] += w2 * bfhi(v2.w);
        acc[0] += w3 * bflo(v3.x); acc[1] += w3 * bfhi(v3.x);
        acc[2] += w3 * bflo(v3.y); acc[3] += w3 * bfhi(v3.y);
        acc[4] += w3 * bflo(v3.z); acc[5] += w3 * bfhi(v3.z);
        acc[6] += w3 * bflo(v3.w); acc[7] += w3 * bfhi(v3.w);
    }
    for (; p < deg; ++p) {
        const int s = slots[base + p];
        const float w = rsqrtf((float)(cnt[s] + 1));
        uint4 v = xw4[(size_t)s * 8 + j];
        acc[0] += w * bflo(v.x); acc[1] += w * bfhi(v.x);
        acc[2] += w * bflo(v.y); acc[3] += w * bfhi(v.y);
        acc[4] += w * bflo(v.z); acc[5] += w * bfhi(v.z);
        acc[6] += w * bflo(v.w); acc[7] += w * bfhi(v.w);
    }
    uint4 vs = xw4[(size_t)node * 8 + j];
    float self[8] = { bflo(vs.x), bfhi(vs.x), bflo(vs.y), bfhi(vs.y),
                      bflo(vs.z), bfhi(vs.z), bflo(vs.w), bfhi(vs.w) };
    const float4 blo = ((const float4*)bias)[2 * j];
    const float4 bhi = ((const float4*)bias)[2 * j + 1];
    const float bb[8] = { blo.x, blo.y, blo.z, blo.w, bhi.x, bhi.y, bhi.z, bhi.w };
    const float dii = di * di;
    float o[8];
#pragma unroll
    for (int i = 0; i < 8; ++i) o[i] = di * acc[i] + dii * self[i] + bb[i];
    float* ep = e3 + (size_t)node * 64 + j * 8;
    ((float4*)ep)[0] = make_float4(o[0], o[1], o[2], o[3]);
    ((float4*)ep)[1] = make_float4(o[4], o[5], o[6], o[7]);
    // fused log_softmax over the 8-lane group (lanes of one node are consecutive)
    float m = o[0];
#pragma unroll
    for (int i = 1; i < 8; ++i) m = fmaxf(m, o[i]);
#pragma unroll
    for (int off = 1; off < 8; off <<= 1) m = fmaxf(m, __shfl_xor(m, off, 64));
    float s = 0.f;
#pragma unroll
    for (int i = 0; i < 8; ++i) s += expf(o[i] - m);
#pragma unroll
    for (int off = 1; off < 8; off <<= 1) s += __shfl_xor(s, off, 64);
    const float ls = m + logf(s);
    float* lp = logp + (size_t)node * 64 + j * 8;
    ((float4*)lp)[0] = make_float4(o[0] - ls, o[1] - ls, o[2] - ls, o[3] - ls);
    ((float4*)lp)[1] = make_float4(o[4] - ls, o[5] - ls, o[6] - ls, o[7] - ls);
}

// ---------------- driver ----------------
extern "C" void kernel_launch(void* const* d_in, const int* in_sizes, int n_in,
                              void* d_out, int out_size, void* d_ws, size_t ws_size,
                              hipStream_t stream) {
    const float* x  = (const float*)d_in[0];
    const void*  ei = d_in[1];
    const float* W1 = (const float*)d_in[2];
    const float* b1 = (const float*)d_in[3];
    const float* W2 = (const float*)d_in[4];
    const float* b2 = (const float*)d_in[5];
    const float* W3 = (const float*)d_in[6];
    const float* b3 = (const float*)d_in[7];
    float* out = (float*)d_out;

    const int N = in_sizes[0] / 128;   // 50000
    const int E = in_sizes[1] / 2;     // 800000

    char* w = (char*)d_ws;
    size_t off = 0;
    auto alloc = [&](size_t bytes) -> void* {
        void* p = w + off;
        off = (off + bytes + 255) & ~(size_t)255;
        return p;
    };
    int*    flag   = (int*)alloc(4);
    int*    cnt    = (int*)alloc((size_t)N * 4);
    int*    slots  = (int*)alloc((size_t)N * SLOT_CAP * 4);   // 12.8 MB
    ushort* xw     = (ushort*)alloc((size_t)N * 128 * 2);     // bf16 GEMM output
    ushort* xwb    = (ushort*)alloc((size_t)N * 128 * 2);     // bf16 relu'd agg output
    ushort* Wt1    = (ushort*)alloc(16384 * 2);
    ushort* Wt2    = (ushort*)alloc(16384 * 2);
    ushort* Wt3    = (ushort*)alloc(8192 * 2);

    float* logp = out;
    float* e1 = out + (size_t)N * 64;
    float* e2 = e1 + (size_t)N * 128;
    float* e3 = e2 + (size_t)N * 128;

    const int nzb = (N + 255) / 256;

    prep_kernel<<<nzb + 161, 256, 0, stream>>>(cnt, N, W1, W2, W3, Wt1, Wt2, Wt3,
                                               ei, flag);
    fillslots_kernel<<<(E + 255) / 256, 256, 0, stream>>>(ei, flag, cnt, slots, E);

    const int gblocks = (N + 127) / 128;
    // layer 1
    mfma_gemm_f32_kernel<<<gblocks, 256, 0, stream>>>(x, Wt1, xw, N);
    agg12_kernel<<<(N + 15) / 16, 256, 0, stream>>>(xw, cnt, slots, b1, e1, xwb, N);
    // layer 2
    mfma_gemm_b_kernel<128><<<gblocks, 256, 0, stream>>>(xwb, Wt2, xw, N);
    agg12_kernel<<<(N + 15) / 16, 256, 0, stream>>>(xw, cnt, slots, b2, e2, xwb, N);
    // layer 3 (Dout=64) + log_softmax
    mfma_gemm_b_kernel<64><<<gblocks, 256, 0, stream>>>(xwb, Wt3, xw, N);
    agg3_lsm_kernel<<<(N + 31) / 32, 256, 0, stream>>>(xw, cnt, slots, b3, e3, logp, N);
}

// Round 5
// 270.304 us; speedup vs baseline: 1.4436x; 1.0196x over previous
//
#include <hip/hip_runtime.h>

// GCN_4492535792198: 3-layer GCN forward on MI355X (gfx950).
// N=50000, E=800000, D: 128->128->64. Outputs: logp[N,64], e1[N,128], e2[N,128], e3[N,64].
// R7 == R6 with macro fix (ACC8 param 'w' collided with member '.w' via preprocessor).
// R6: (a) XCD-partitioned slot fill — block b handles dst-partition (b&7) over edge
//   chunk (b>>3); partition slot region (1.6MB) is L2-resident on one XCD so scatter
//   writes combine in L2 (R5 counters: 48MB WRITE for 3.2MB payload, 0.9TB/s, 58us).
//   (b) agg gather pipeline deepened 4 -> 8 outstanding rows (latency-bound test).

typedef __attribute__((ext_vector_type(8))) short short8;   // 8 x bf16 (4 VGPRs)
typedef __attribute__((ext_vector_type(4))) float f32x4;

#define SLOT_CAP 64
#define FILL_CHUNK 2048

__device__ __forceinline__ ushort f2bf(float f) {
    union { float f; unsigned u; } a; a.f = f;
    unsigned r = a.u + 0x7fffu + ((a.u >> 16) & 1u);   // RNE (finite data)
    return (ushort)(r >> 16);
}
__device__ __forceinline__ float bflo(unsigned u) { return __uint_as_float(u << 16); }
__device__ __forceinline__ float bfhi(unsigned u) { return __uint_as_float(u & 0xffff0000u); }

__device__ __forceinline__ int edge_at(const void* ei, int is64, long long i) {
    if (is64) return (int)((const long long*)ei)[i];
    return ((const int*)ei)[i];
}

// ---------------- prep: zero cnt + weight transpose + detect dtype ----------------
__global__ void prep_kernel(int* __restrict__ cnt, int n,
                            const float* __restrict__ W1, const float* __restrict__ W2,
                            const float* __restrict__ W3, ushort* __restrict__ Wt1,
                            ushort* __restrict__ Wt2, ushort* __restrict__ Wt3,
                            const void* ei, int* __restrict__ flag) {
    const int nzb = (n + 255) >> 8;
    const int b = blockIdx.x, tid = threadIdx.x;
    if (b < nzb) {
        int i = b * 256 + tid;
        if (i < n) cnt[i] = 0;
        return;
    }
    if (b == nzb + 160) {                 // dtype-detect block
        if (tid < 64) {
            long long v = ((const long long*)ei)[tid];
            int bad = (v < 0 || v >= (1LL << 32)) ? 1 : 0;
            unsigned long long m = __ballot(bad);
            if (tid == 0) *flag = (m == 0ULL) ? 1 : 0;   // 1 => int64
        }
        return;
    }
    int i = (b - nzb) * 256 + tid;
    if (i < 16384) {
        int nn = i >> 7, k = i & 127;
        Wt1[i] = f2bf(W1[k * 128 + nn]);
    } else if (i < 32768) {
        int j = i - 16384; int nn = j >> 7, k = j & 127;
        Wt2[j] = f2bf(W2[k * 128 + nn]);
    } else if (i < 40960) {
        int j = i - 32768; int nn = j >> 7, k = j & 127;
        Wt3[j] = f2bf(W3[k * 64 + nn]);
    }
}

// ---------------- XCD-partitioned slot fill ----------------
// Block b: partition p = b&7 (dst range [p*nper, (p+1)*nper)), edge chunk c = b>>3.
__global__ void fillslots_kernel(const void* ei, const int* __restrict__ flag,
                                 int* __restrict__ cnt, int* __restrict__ slots,
                                 int E, int nper) {
    const int part = blockIdx.x & 7;
    const int lo = part * nper;
    const int hi = lo + nper;
    const int e0 = (blockIdx.x >> 3) * FILL_CHUNK;
    const int e1 = (e0 + FILL_CHUNK < E) ? e0 + FILL_CHUNK : E;
    const int is64 = flag[0];
    for (int e = e0 + threadIdx.x; e < e1; e += 256) {
        int d = edge_at(ei, is64, (long long)E + e);
        if (d >= lo && d < hi) {
            int s = edge_at(ei, is64, e);
            int p = atomicAdd(&cnt[d], 1);
            if (p < SLOT_CAP) slots[(d << 6) + p] = s;
        }
    }
}

// ---------------- MFMA GEMM (fp32 input): xw[M,128](bf16) = A[M,128] @ W ----------
__global__ __launch_bounds__(256) void mfma_gemm_f32_kernel(
    const float* __restrict__ A, const ushort* __restrict__ Wt,
    ushort* __restrict__ xw, int M) {
    constexpr int NT = 8;
    __shared__ ushort As[128 * 136];
    __shared__ ushort Ws[128 * 136];
    const int tid = threadIdx.x;
    const int r0 = blockIdx.x * 128;
    const int wid = tid >> 6;
    const int lane = tid & 63;
    const int m = lane & 15, quad = lane >> 4;

#pragma unroll
    for (int i = 0; i < 16; ++i) {
        int li = tid + i * 256;             // 0..4095 float4 slots
        int row = li >> 5, c4 = li & 31;
        float4 v = make_float4(0.f, 0.f, 0.f, 0.f);
        int gr = r0 + row;
        if (gr < M) v = ((const float4*)(A + (size_t)gr * 128))[c4];
        ushort4 u;
        u.x = f2bf(v.x); u.y = f2bf(v.y); u.z = f2bf(v.z); u.w = f2bf(v.w);
        *(ushort4*)&As[row * 136 + c4 * 4] = u;
    }
#pragma unroll
    for (int i = 0; i < 8; ++i) {
        int li = tid + i * 256;             // uint4 slots over 128*16
        int n = li >> 4, c = li & 15;
        uint4 v = ((const uint4*)Wt)[li];
        *(uint4*)&Ws[n * 136 + c * 8] = v;
    }
    __syncthreads();

    f32x4 acc[2][NT];
#pragma unroll
    for (int rt = 0; rt < 2; ++rt)
#pragma unroll
        for (int nt = 0; nt < NT; ++nt) acc[rt][nt] = (f32x4){0.f, 0.f, 0.f, 0.f};

#pragma unroll
    for (int kt = 0; kt < 4; ++kt) {
        const int ko = kt * 32 + quad * 8;
        short8 af0 = *(const short8*)&As[(wid * 32 + m) * 136 + ko];
        short8 af1 = *(const short8*)&As[(wid * 32 + 16 + m) * 136 + ko];
        short8 bf_[NT];
#pragma unroll
        for (int nt = 0; nt < NT; ++nt)
            bf_[nt] = *(const short8*)&Ws[(nt * 16 + m) * 136 + ko];
#pragma unroll
        for (int nt = 0; nt < NT; ++nt) {
            acc[0][nt] = __builtin_amdgcn_mfma_f32_16x16x32_bf16(af0, bf_[nt], acc[0][nt], 0, 0, 0);
            acc[1][nt] = __builtin_amdgcn_mfma_f32_16x16x32_bf16(af1, bf_[nt], acc[1][nt], 0, 0, 0);
        }
    }
#pragma unroll
    for (int rt = 0; rt < 2; ++rt)
#pragma unroll
        for (int nt = 0; nt < NT; ++nt)
#pragma unroll
            for (int i = 0; i < 4; ++i) {
                int row = r0 + wid * 32 + rt * 16 + quad * 4 + i;
                if (row < M) xw[(size_t)row * 128 + nt * 16 + m] = f2bf(acc[rt][nt][i]);
            }
}

// ---------------- MFMA GEMM (bf16 input, pre-relu'd): xw = A @ W ----------------
template <int DOUT>
__global__ __launch_bounds__(256) void mfma_gemm_b_kernel(
    const ushort* __restrict__ A, const ushort* __restrict__ Wt,
    ushort* __restrict__ xw, int M) {
    constexpr int NT = DOUT / 16;
    __shared__ ushort As[128 * 136];
    __shared__ ushort Ws[DOUT * 136];
    const int tid = threadIdx.x;
    const int r0 = blockIdx.x * 128;
    const int wid = tid >> 6;
    const int lane = tid & 63;
    const int m = lane & 15, quad = lane >> 4;

#pragma unroll
    for (int i = 0; i < 8; ++i) {
        int li = tid + i * 256;             // 2048 uint4 slots (128 rows x 16)
        int row = li >> 4, c = li & 15;
        uint4 v = make_uint4(0u, 0u, 0u, 0u);
        int gr = r0 + row;
        if (gr < M) v = ((const uint4*)A)[(size_t)gr * 16 + c];
        *(uint4*)&As[row * 136 + c * 8] = v;
    }
#pragma unroll
    for (int i = 0; i < DOUT / 16; ++i) {
        int li = tid + i * 256;
        int n = li >> 4, c = li & 15;
        uint4 v = ((const uint4*)Wt)[li];
        *(uint4*)&Ws[n * 136 + c * 8] = v;
    }
    __syncthreads();

    f32x4 acc[2][NT];
#pragma unroll
    for (int rt = 0; rt < 2; ++rt)
#pragma unroll
        for (int nt = 0; nt < NT; ++nt) acc[rt][nt] = (f32x4){0.f, 0.f, 0.f, 0.f};

#pragma unroll
    for (int kt = 0; kt < 4; ++kt) {
        const int ko = kt * 32 + quad * 8;
        short8 af0 = *(const short8*)&As[(wid * 32 + m) * 136 + ko];
        short8 af1 = *(const short8*)&As[(wid * 32 + 16 + m) * 136 + ko];
        short8 bf_[NT];
#pragma unroll
        for (int nt = 0; nt < NT; ++nt)
            bf_[nt] = *(const short8*)&Ws[(nt * 16 + m) * 136 + ko];
#pragma unroll
        for (int nt = 0; nt < NT; ++nt) {
            acc[0][nt] = __builtin_amdgcn_mfma_f32_16x16x32_bf16(af0, bf_[nt], acc[0][nt], 0, 0, 0);
            acc[1][nt] = __builtin_amdgcn_mfma_f32_16x16x32_bf16(af1, bf_[nt], acc[1][nt], 0, 0, 0);
        }
    }
#pragma unroll
    for (int rt = 0; rt < 2; ++rt)
#pragma unroll
        for (int nt = 0; nt < NT; ++nt)
#pragma unroll
            for (int i = 0; i < 4; ++i) {
                int row = r0 + wid * 32 + rt * 16 + quad * 4 + i;
                if (row < M) xw[(size_t)row * DOUT + nt * 16 + m] = f2bf(acc[rt][nt][i]);
            }
}

// NOTE: parameter names must not collide with vector member names (.x/.y/.z/.w).
#define ACC8(W_, V_)                                               \
    acc[0] += W_ * bflo(V_.x); acc[1] += W_ * bfhi(V_.x);          \
    acc[2] += W_ * bflo(V_.y); acc[3] += W_ * bfhi(V_.y);          \
    acc[4] += W_ * bflo(V_.z); acc[5] += W_ * bfhi(V_.z);          \
    acc[6] += W_ * bflo(V_.w); acc[7] += W_ * bfhi(V_.w);

// ---------------- aggregation layers 1/2 (bf16 gather, slot-based, 8-deep) -------
__global__ __launch_bounds__(256) void agg12_kernel(
    const ushort* __restrict__ xw, const int* __restrict__ cnt,
    const int* __restrict__ slots, const float* __restrict__ bias,
    float* __restrict__ out, ushort* __restrict__ xwb, int n) {
    const int tid = threadIdx.x;
    const int node = blockIdx.x * 16 + (tid >> 4);
    const int j = tid & 15;
    if (node >= n) return;
    const uint4* xw4 = (const uint4*)xw;   // row pitch = 16 uint4
    const int degf = cnt[node];
    const int deg = (degf < SLOT_CAP) ? degf : SLOT_CAP;
    const float di = rsqrtf((float)(degf + 1));
    const int base = node << 6;
    float acc[8];
#pragma unroll
    for (int i = 0; i < 8; ++i) acc[i] = 0.f;

    int p = 0;
    while (p + 8 <= deg) {
        const int4 ca = *(const int4*)&slots[base + p];
        const int4 cb = *(const int4*)&slots[base + p + 4];
        const int g0 = cnt[ca.x], g1 = cnt[ca.y], g2 = cnt[ca.z], g3 = cnt[ca.w];
        const int g4 = cnt[cb.x], g5 = cnt[cb.y], g6 = cnt[cb.z], g7 = cnt[cb.w];
        uint4 v0 = xw4[(size_t)ca.x * 16 + j];
        uint4 v1 = xw4[(size_t)ca.y * 16 + j];
        uint4 v2 = xw4[(size_t)ca.z * 16 + j];
        uint4 v3 = xw4[(size_t)ca.w * 16 + j];
        uint4 v4 = xw4[(size_t)cb.x * 16 + j];
        uint4 v5 = xw4[(size_t)cb.y * 16 + j];
        uint4 v6 = xw4[(size_t)cb.z * 16 + j];
        uint4 v7 = xw4[(size_t)cb.w * 16 + j];
        const float w0 = rsqrtf((float)(g0 + 1));
        const float w1 = rsqrtf((float)(g1 + 1));
        const float w2 = rsqrtf((float)(g2 + 1));
        const float w3 = rsqrtf((float)(g3 + 1));
        const float w4 = rsqrtf((float)(g4 + 1));
        const float w5 = rsqrtf((float)(g5 + 1));
        const float w6 = rsqrtf((float)(g6 + 1));
        const float w7 = rsqrtf((float)(g7 + 1));
        ACC8(w0, v0) ACC8(w1, v1) ACC8(w2, v2) ACC8(w3, v3)
        ACC8(w4, v4) ACC8(w5, v5) ACC8(w6, v6) ACC8(w7, v7)
        p += 8;
    }
    if (p + 4 <= deg) {
        const int4 ca = *(const int4*)&slots[base + p];
        const int g0 = cnt[ca.x], g1 = cnt[ca.y], g2 = cnt[ca.z], g3 = cnt[ca.w];
        uint4 v0 = xw4[(size_t)ca.x * 16 + j];
        uint4 v1 = xw4[(size_t)ca.y * 16 + j];
        uint4 v2 = xw4[(size_t)ca.z * 16 + j];
        uint4 v3 = xw4[(size_t)ca.w * 16 + j];
        const float w0 = rsqrtf((float)(g0 + 1));
        const float w1 = rsqrtf((float)(g1 + 1));
        const float w2 = rsqrtf((float)(g2 + 1));
        const float w3 = rsqrtf((float)(g3 + 1));
        ACC8(w0, v0) ACC8(w1, v1) ACC8(w2, v2) ACC8(w3, v3)
        p += 4;
    }
    for (; p < deg; ++p) {
        const int s = slots[base + p];
        const float ww = rsqrtf((float)(cnt[s] + 1));
        uint4 vv = xw4[(size_t)s * 16 + j];
        ACC8(ww, vv)
    }
    uint4 vs = xw4[(size_t)node * 16 + j];
    float self[8] = { bflo(vs.x), bfhi(vs.x), bflo(vs.y), bfhi(vs.y),
                      bflo(vs.z), bfhi(vs.z), bflo(vs.w), bfhi(vs.w) };
    const float4 blo = ((const float4*)bias)[2 * j];
    const float4 bhi = ((const float4*)bias)[2 * j + 1];
    const float bb[8] = { blo.x, blo.y, blo.z, blo.w, bhi.x, bhi.y, bhi.z, bhi.w };
    const float dii = di * di;
    float o[8];
#pragma unroll
    for (int i = 0; i < 8; ++i) o[i] = di * acc[i] + dii * self[i] + bb[i];
    float* op = out + (size_t)node * 128 + j * 8;
    ((float4*)op)[0] = make_float4(o[0], o[1], o[2], o[3]);
    ((float4*)op)[1] = make_float4(o[4], o[5], o[6], o[7]);
    // relu'd bf16 copy for the next GEMM
    union { ushort us[8]; uint4 v; } pk;
#pragma unroll
    for (int i = 0; i < 8; ++i) pk.us[i] = f2bf(fmaxf(o[i], 0.f));
    ((uint4*)xwb)[(size_t)node * 16 + j] = pk.v;
}

// ---------------- aggregation layer 3 (Dout=64) + fused log_softmax --------------
__global__ __launch_bounds__(256) void agg3_lsm_kernel(
    const ushort* __restrict__ xw, const int* __restrict__ cnt,
    const int* __restrict__ slots, const float* __restrict__ bias,
    float* __restrict__ e3, float* __restrict__ logp, int n) {
    const int tid = threadIdx.x;
    const int node = blockIdx.x * 32 + (tid >> 3);
    const int j = tid & 7;
    if (node >= n) return;
    const uint4* xw4 = (const uint4*)xw;   // row pitch = 8 uint4
    const int degf = cnt[node];
    const int deg = (degf < SLOT_CAP) ? degf : SLOT_CAP;
    const float di = rsqrtf((float)(degf + 1));
    const int base = node << 6;
    float acc[8];
#pragma unroll
    for (int i = 0; i < 8; ++i) acc[i] = 0.f;

    int p = 0;
    while (p + 8 <= deg) {
        const int4 ca = *(const int4*)&slots[base + p];
        const int4 cb = *(const int4*)&slots[base + p + 4];
        const int g0 = cnt[ca.x], g1 = cnt[ca.y], g2 = cnt[ca.z], g3 = cnt[ca.w];
        const int g4 = cnt[cb.x], g5 = cnt[cb.y], g6 = cnt[cb.z], g7 = cnt[cb.w];
        uint4 v0 = xw4[(size_t)ca.x * 8 + j];
        uint4 v1 = xw4[(size_t)ca.y * 8 + j];
        uint4 v2 = xw4[(size_t)ca.z * 8 + j];
        uint4 v3 = xw4[(size_t)ca.w * 8 + j];
        uint4 v4 = xw4[(size_t)cb.x * 8 + j];
        uint4 v5 = xw4[(size_t)cb.y * 8 + j];
        uint4 v6 = xw4[(size_t)cb.z * 8 + j];
        uint4 v7 = xw4[(size_t)cb.w * 8 + j];
        const float w0 = rsqrtf((float)(g0 + 1));
        const float w1 = rsqrtf((float)(g1 + 1));
        const float w2 = rsqrtf((float)(g2 + 1));
        const float w3 = rsqrtf((float)(g3 + 1));
        const float w4 = rsqrtf((float)(g4 + 1));
        const float w5 = rsqrtf((float)(g5 + 1));
        const float w6 = rsqrtf((float)(g6 + 1));
        const float w7 = rsqrtf((float)(g7 + 1));
        ACC8(w0, v0) ACC8(w1, v1) ACC8(w2, v2) ACC8(w3, v3)
        ACC8(w4, v4) ACC8(w5, v5) ACC8(w6, v6) ACC8(w7, v7)
        p += 8;
    }
    if (p + 4 <= deg) {
        const int4 ca = *(const int4*)&slots[base + p];
        const int g0 = cnt[ca.x], g1 = cnt[ca.y], g2 = cnt[ca.z], g3 = cnt[ca.w];
        uint4 v0 = xw4[(size_t)ca.x * 8 + j];
        uint4 v1 = xw4[(size_t)ca.y * 8 + j];
        uint4 v2 = xw4[(size_t)ca.z * 8 + j];
        uint4 v3 = xw4[(size_t)ca.w * 8 + j];
        const float w0 = rsqrtf((float)(g0 + 1));
        const float w1 = rsqrtf((float)(g1 + 1));
        const float w2 = rsqrtf((float)(g2 + 1));
        const float w3 = rsqrtf((float)(g3 + 1));
        ACC8(w0, v0) ACC8(w1, v1) ACC8(w2, v2) ACC8(w3, v3)
        p += 4;
    }
    for (; p < deg; ++p) {
        const int s = slots[base + p];
        const float ww = rsqrtf((float)(cnt[s] + 1));
        uint4 vv = xw4[(size_t)s * 8 + j];
        ACC8(ww, vv)
    }
    uint4 vs = xw4[(size_t)node * 8 + j];
    float self[8] = { bflo(vs.x), bfhi(vs.x), bflo(vs.y), bfhi(vs.y),
                      bflo(vs.z), bfhi(vs.z), bflo(vs.w), bfhi(vs.w) };
    const float4 blo = ((const float4*)bias)[2 * j];
    const float4 bhi = ((const float4*)bias)[2 * j + 1];
    const float bb[8] = { blo.x, blo.y, blo.z, blo.w, bhi.x, bhi.y, bhi.z, bhi.w };
    const float dii = di * di;
    float o[8];
#pragma unroll
    for (int i = 0; i < 8; ++i) o[i] = di * acc[i] + dii * self[i] + bb[i];
    float* ep = e3 + (size_t)node * 64 + j * 8;
    ((float4*)ep)[0] = make_float4(o[0], o[1], o[2], o[3]);
    ((float4*)ep)[1] = make_float4(o[4], o[5], o[6], o[7]);
    // fused log_softmax over the 8-lane group
    float m = o[0];
#pragma unroll
    for (int i = 1; i < 8; ++i) m = fmaxf(m, o[i]);
#pragma unroll
    for (int off = 1; off < 8; off <<= 1) m = fmaxf(m, __shfl_xor(m, off, 64));
    float s = 0.f;
#pragma unroll
    for (int i = 0; i < 8; ++i) s += expf(o[i] - m);
#pragma unroll
    for (int off = 1; off < 8; off <<= 1) s += __shfl_xor(s, off, 64);
    const float ls = m + logf(s);
    float* lp = logp + (size_t)node * 64 + j * 8;
    ((float4*)lp)[0] = make_float4(o[0] - ls, o[1] - ls, o[2] - ls, o[3] - ls);
    ((float4*)lp)[1] = make_float4(o[4] - ls, o[5] - ls, o[6] - ls, o[7] - ls);
}

// ---------------- driver ----------------
extern "C" void kernel_launch(void* const* d_in, const int* in_sizes, int n_in,
                              void* d_out, int out_size, void* d_ws, size_t ws_size,
                              hipStream_t stream) {
    const float* x  = (const float*)d_in[0];
    const void*  ei = d_in[1];
    const float* W1 = (const float*)d_in[2];
    const float* b1 = (const float*)d_in[3];
    const float* W2 = (const float*)d_in[4];
    const float* b2 = (const float*)d_in[5];
    const float* W3 = (const float*)d_in[6];
    const float* b3 = (const float*)d_in[7];
    float* out = (float*)d_out;

    const int N = in_sizes[0] / 128;   // 50000
    const int E = in_sizes[1] / 2;     // 800000

    char* w = (char*)d_ws;
    size_t off = 0;
    auto alloc = [&](size_t bytes) -> void* {
        void* p = w + off;
        off = (off + bytes + 255) & ~(size_t)255;
        return p;
    };
    int*    flag   = (int*)alloc(4);
    int*    cnt    = (int*)alloc((size_t)N * 4);
    int*    slots  = (int*)alloc((size_t)N * SLOT_CAP * 4);   // 12.8 MB
    ushort* xw     = (ushort*)alloc((size_t)N * 128 * 2);     // bf16 GEMM output
    ushort* xwb    = (ushort*)alloc((size_t)N * 128 * 2);     // bf16 relu'd agg output
    ushort* Wt1    = (ushort*)alloc(16384 * 2);
    ushort* Wt2    = (ushort*)alloc(16384 * 2);
    ushort* Wt3    = (ushort*)alloc(8192 * 2);

    float* logp = out;
    float* e1 = out + (size_t)N * 64;
    float* e2 = e1 + (size_t)N * 128;
    float* e3 = e2 + (size_t)N * 128;

    const int nzb = (N + 255) / 256;
    const int nper = (N + 7) / 8;                      // dst-partition width
    const int nch = (E + FILL_CHUNK - 1) / FILL_CHUNK; // edge chunks

    prep_kernel<<<nzb + 161, 256, 0, stream>>>(cnt, N, W1, W2, W3, Wt1, Wt2, Wt3,
                                               ei, flag);
    fillslots_kernel<<<nch * 8, 256, 0, stream>>>(ei, flag, cnt, slots, E, nper);

    const int gblocks = (N + 127) / 128;
    // layer 1
    mfma_gemm_f32_kernel<<<gblocks, 256, 0, stream>>>(x, Wt1, xw, N);
    agg12_kernel<<<(N + 15) / 16, 256, 0, stream>>>(xw, cnt, slots, b1, e1, xwb, N);
    // layer 2
    mfma_gemm_b_kernel<128><<<gblocks, 256, 0, stream>>>(xwb, Wt2, xw, N);
    agg12_kernel<<<(N + 15) / 16, 256, 0, stream>>>(xw, cnt, slots, b2, e2, xwb, N);
    // layer 3 (Dout=64) + log_softmax
    mfma_gemm_b_kernel<64><<<gblocks, 256, 0, stream>>>(xwb, Wt3, xw, N);
    agg3_lsm_kernel<<<(N + 31) / 32, 256, 0, stream>>>(xw, cnt, slots, b3, e3, logp, N);
}